// Round 11
// baseline (235.219 us; speedup 1.0000x reference)
//
#include <hip/hip_runtime.h>
#include <hip/hip_bf16.h>
#include <cstddef>
#include <cstdint>

// Problem constants
#define Bn   4
#define Tn   1024
#define HID  1024
#define NH   64
#define HS   16
#define NA   1024

#define MAGIC 0x13579BDFu

typedef short v8s __attribute__((ext_vector_type(8)));
typedef float v4f __attribute__((ext_vector_type(4)));

typedef __attribute__((address_space(1))) void* as1_void;
typedef __attribute__((address_space(3))) void* as3_void;

__device__ __forceinline__ void gload_lds16(const void* g, void* l) {
    __builtin_amdgcn_global_load_lds((as1_void)(void*)g, (as3_void)l, 16, 0, 0);
}

__device__ __forceinline__ short f2bf(float f) {
    __hip_bfloat16 h = __float2bfloat16(f);
    return *reinterpret_cast<short*>(&h);
}
__device__ __forceinline__ float bf2f(short s) {
    __hip_bfloat16 h = *reinterpret_cast<__hip_bfloat16*>(&s);
    return __bfloat162float(h);
}

// ---------------------------------------------------------------------------
// prep: fused build_xs (blocks 0..4095) + weight transpose/convert (4096..8191)
// Block 0 also zeroes the scan flags (stream-ordered well before scan_fused).
// ---------------------------------------------------------------------------
__global__ __launch_bounds__(256)
void prep(const float* __restrict__ x,
          const float* __restrict__ W0, const float* __restrict__ W1,
          const float* __restrict__ W2, const float* __restrict__ W3,
          short* __restrict__ xs, short* __restrict__ Wt,
          unsigned* __restrict__ flags)
{
    __shared__ float tile[32][33];
    const int bid = blockIdx.x;
    const int tid = threadIdx.x;
    if (bid < 4096) {
        if (bid == 0) flags[tid] = 0u;   // clear lookback flags (256 words)
        int idx = bid * 256 + tid;
        int m  = idx >> 8;
        int c4 = (idx & 255) * 4;
        int t  = m & (Tn - 1);
        float4 v;
        if (c4 < HID / 2) {
            if (t == 0) v = make_float4(0.f, 0.f, 0.f, 0.f);
            else        v = *(const float4*)(x + (size_t)(m - 1) * HID + c4);
        } else {
            v = *(const float4*)(x + (size_t)m * HID + c4);
        }
        short4 o;
        o.x = f2bf(v.x); o.y = f2bf(v.y); o.z = f2bf(v.z); o.w = f2bf(v.w);
        *(short4*)(xs + (size_t)m * HID + c4) = o;
    } else {
        int b2 = bid - 4096;
        int z  = b2 >> 10;
        int rem = b2 & 1023;
        const float* W = (z == 0) ? W0 : (z == 1) ? W1 : (z == 2) ? W2 : W3;
        short* dst = Wt + (size_t)z * 1024 * 1024;
        int k0 = (rem & 31) * 32;
        int n0 = (rem >> 5) * 32;
        int tx = tid & 31;
        int ty = tid >> 5;
        #pragma unroll
        for (int j = 0; j < 4; ++j)
            tile[ty + 8 * j][tx] = W[(size_t)(k0 + ty + 8 * j) * NA + n0 + tx];
        __syncthreads();
        #pragma unroll
        for (int j = 0; j < 4; ++j)
            dst[(size_t)(n0 + ty + 8 * j) * HID + k0 + tx] = f2bf(tile[tx][ty + 8 * j]);
    }
}

// ---------------------------------------------------------------------------
// 3-stage-pipelined MFMA GEMM (round-8 best-measured variant), 16x16x32 bf16.
// Tile 128 x TN, BK=32, 256 thr = 4 waves; one barrier per k-iter.
// SWAPPED-OPERAND mfma(bfr, af, acc): acc[mt][nt][reg] =
//   C[m = wm+mt*16+(lane&15)][n = wn+nt*16+(lane>>4)*4+reg] -> packed stores.
// LDS swizzle slot=(q+(r>>1))&3, inverse applied in the global gather.
// EPI 0 (TN=128, KVR fused, type=bn>>10): via LDS transpose tile, int4 stores.
// EPI 1 (TN=64): fout = (acc + b0[n]) * gamma[m&1023], float4 stores.
// ---------------------------------------------------------------------------
template<int EPI, int TN>
__global__ __launch_bounds__(256)
void gemm_db(const short* __restrict__ A, const short* __restrict__ Bt,
             const float* __restrict__ b0, const float* __restrict__ b1,
             const float* __restrict__ b2,
             short* __restrict__ kout, short* __restrict__ vout,
             short* __restrict__ sout, float* __restrict__ fout,
             const float* __restrict__ gamma)
{
    constexpr int NT  = TN / 32;          // n-tiles per wave
    constexpr int BI  = TN / 64;          // B staging insts per wave
    constexpr int SA  = 128 * 32;         // shorts per A stage
    constexpr int SB  = TN * 32;          // shorts per B stage
    constexpr int WAITN = 2 + BI;         // insts per stage per wave
    __shared__ short As[3 * SA];
    __shared__ short Bs[3 * SB];

    const int tid  = threadIdx.x;
    const int wave = tid >> 6;
    const int lane = tid & 63;

    // XCD-friendly block swizzle
    int id = blockIdx.x;
    int brow, bcol;
    if (TN == 128) { int grp = id / 192, l = id % 192; brow = grp * 8 + (l & 7); bcol = (l >> 3) % 24; }
    else           { int grp = id / 128, l = id % 128; brow = grp * 8 + (l & 7); bcol = l >> 3; }
    const int bm = brow * 128;
    const int bn = bcol * TN;

    const int wm = (wave & 1) * 64;
    const int wn = (wave >> 1) * (TN / 2);
    const int lm = lane & 15;
    const int lq = lane >> 4;
    const int lr = lane >> 2;            // 16 rows per staging inst
    const int l4 = lane & 3;             // chunk slot within row

    v4f acc[4][NT];
    #pragma unroll
    for (int i = 0; i < 4; ++i)
        #pragma unroll
        for (int j = 0; j < NT; ++j) acc[i][j] = (v4f){0.f, 0.f, 0.f, 0.f};

    // staging pointers with inverse swizzle q = (slot - (r>>1)) & 3
    const short* ag[2];
    int adst[2];
    #pragma unroll
    for (int i = 0; i < 2; ++i) {
        int r = wave * 32 + i * 16 + lr;
        int q = (l4 - (r >> 1)) & 3;
        ag[i]  = A + (size_t)(bm + r) * 1024 + q * 8;
        adst[i] = (wave * 32 + i * 16) * 32;        // wave-uniform base
    }
    const short* bg[BI];
    int bdst[BI];
    #pragma unroll
    for (int i = 0; i < BI; ++i) {
        int r = wave * (TN / 4) + i * 16 + lr;
        int q = (l4 - (r >> 1)) & 3;
        bg[i]  = Bt + (size_t)(bn + r) * 1024 + q * 8;
        bdst[i] = (wave * (TN / 4) + i * 16) * 32;
    }
    // fragment LDS offsets: chunk lq of row r at slot (lq + (r>>1)) & 3
    int afo[4], bfo[NT];
    #pragma unroll
    for (int t = 0; t < 4; ++t) {
        int r = wm + t * 16 + lm;
        afo[t] = r * 32 + ((lq + (r >> 1)) & 3) * 8;
    }
    #pragma unroll
    for (int nt = 0; nt < NT; ++nt) {
        int r = wn + nt * 16 + lm;
        bfo[nt] = r * 32 + ((lq + (r >> 1)) & 3) * 8;
    }

    // prologue: stage k-iters 0 and 1 into buffers 0 and 1
    #pragma unroll
    for (int s = 0; s < 2; ++s) {
        int k = s * 32;
        #pragma unroll
        for (int i = 0; i < 2; ++i)  gload_lds16(ag[i] + k, &As[s * SA + adst[i]]);
        #pragma unroll
        for (int i = 0; i < BI; ++i) gload_lds16(bg[i] + k, &Bs[s * SB + bdst[i]]);
    }

    int coffA = 0, coffB = 0;            // consume-buffer offsets
    int poffA = 2 * SA, poffB = 2 * SB;  // prefetch-buffer offsets

    for (int it = 0; it < 32; ++it) {
        if (it < 31) asm volatile("s_waitcnt vmcnt(%0)" :: "i"(WAITN) : "memory");
        else         asm volatile("s_waitcnt vmcnt(0)" ::: "memory");
        asm volatile("s_barrier" ::: "memory");

        if (it < 30) {
            int k2 = (it + 2) * 32;
            #pragma unroll
            for (int i = 0; i < 2; ++i)  gload_lds16(ag[i] + k2, &As[poffA + adst[i]]);
            #pragma unroll
            for (int i = 0; i < BI; ++i) gload_lds16(bg[i] + k2, &Bs[poffB + bdst[i]]);
        }

        v8s af[4], bfr[NT];
        #pragma unroll
        for (int t = 0; t < 4; ++t)
            af[t] = *(const v8s*)&As[coffA + afo[t]];
        #pragma unroll
        for (int nt = 0; nt < NT; ++nt)
            bfr[nt] = *(const v8s*)&Bs[coffB + bfo[nt]];
        #pragma unroll
        for (int mt = 0; mt < 4; ++mt)
            #pragma unroll
            for (int nt = 0; nt < NT; ++nt)
                acc[mt][nt] = __builtin_amdgcn_mfma_f32_16x16x32_bf16(
                    bfr[nt], af[mt], acc[mt][nt], 0, 0, 0);

        coffA += SA; if (coffA == 3 * SA) coffA = 0;
        coffB += SB; if (coffB == 3 * SB) coffB = 0;
        poffA += SA; if (poffA == 3 * SA) poffA = 0;
        poffB += SB; if (poffB == 3 * SB) poffB = 0;
    }

    if (EPI == 0) {
        __syncthreads();                 // staging LDS dead; reuse as tile
        short* tile = As;                // 128 rows x stride 136 shorts (34 KB)
        const int type = bn >> 10;
        const int cb = bn & 1023;
        const float* bias = (type == 0) ? b0 : (type == 1) ? b1 : b2;
        #pragma unroll
        for (int mt = 0; mt < 4; ++mt) {
            int ml = wm + mt * 16 + lm;
            #pragma unroll
            for (int nt = 0; nt < NT; ++nt) {
                int nl = wn + nt * 16 + lq * 4;
                float4 bv4 = *(const float4*)&bias[cb + nl];
                short4 o;
                #pragma unroll
                for (int r = 0; r < 4; ++r) {
                    float v = acc[mt][nt][r] + ((const float*)&bv4)[r];
                    if (type == 0) {
                        v = fminf(fmaxf(v, -60.f), 30.f);
                        v = __expf(v);
                    } else if (type == 2) {
                        v = __builtin_amdgcn_rcpf(1.f + __expf(-v));
                    }
                    ((short*)&o)[r] = f2bf(v);
                }
                *(short4*)&tile[ml * 136 + nl] = o;
            }
        }
        __syncthreads();
        short* outp = (type == 0) ? kout : (type == 1) ? vout : sout;
        const int rml = tid >> 4;
        const int rnl = (tid & 15) * 8;
        #pragma unroll
        for (int p = 0; p < 8; ++p) {
            int ml = p * 16 + rml;
            int4 d = *(const int4*)&tile[ml * 136 + rnl];
            *(int4*)&outp[(size_t)(bm + ml) * 1024 + cb + rnl] = d;
        }
    } else {
        #pragma unroll
        for (int mt = 0; mt < 4; ++mt) {
            int m = bm + wm + mt * 16 + lm;
            float g = gamma[m & (Tn - 1)];
            #pragma unroll
            for (int nt = 0; nt < NT; ++nt) {
                int n0 = bn + wn + nt * 16 + lq * 4;
                float4 bv4 = *(const float4*)&b0[n0];
                float4 o;
                o.x = (acc[mt][nt][0] + bv4.x) * g;
                o.y = (acc[mt][nt][1] + bv4.y) * g;
                o.z = (acc[mt][nt][2] + bv4.z) * g;
                o.w = (acc[mt][nt][3] + bv4.w) * g;
                *(float4*)&fout[(size_t)m * 1024 + n0] = o;
            }
        }
    }
}

// ---------------------------------------------------------------------------
// Single-pass decoupled-lookback scan (replaces scanA + scanC).
// w[t,u] = r_h^(t-u), r_h = time_w[h,1022]:
//   S[t] = r*S[t-1] + alpha[t]*kexp[t]*v[t];  ks[t] = ks[t-1] + kexp[t]
// 256 blocks = 1/CU, all co-resident.  Block (seg,g): seg = bid>>3 (0..31,
// 32 t each), g = bid&7 (512 channels: b = g>>1, chalf = g&1).
// Phase 1: local aggregate -> states[seg][col] + threadfence + release flag.
// Phase 2: acquire predecessors' flags in order, combine exclusive prefix
// (identical math to old scanC), then emit outputs re-reading the L1-hot slice.
// Flags poisoned 0xAA by harness each launch (!= MAGIC); prep also zeroes.
// ---------------------------------------------------------------------------
__global__ __launch_bounds__(256)
void scan_fused(const short* __restrict__ kexp, const short* __restrict__ vbuf,
                const short* __restrict__ sigr,
                const float* __restrict__ time_w, const float* __restrict__ alpha,
                const float* __restrict__ beta,
                float2* __restrict__ states, unsigned* __restrict__ flags,
                short* __restrict__ out)
{
    const int bid = blockIdx.x;          // 0..255
    const int g   = bid & 7;
    const int seg = bid >> 3;
    const int tid = threadIdx.x;
    const int b   = g >> 1;
    const int c2  = (g & 1) * 512 + tid * 2;
    const int col = b * 1024 + c2;
    const int h   = c2 >> 4;
    const float r = time_w[h * Tn + (Tn - 2)];
    const int t0 = seg * 32;
    const size_t base = ((size_t)(b * Tn + t0)) * NA + c2;
    const float* ap = alpha + h * Tn + t0;

    // ---- phase 1: local segment aggregate ----
    float S0 = 0.f, S1 = 0.f, ks0 = 0.f, ks1 = 0.f;
    #pragma unroll 4
    for (int i = 0; i < 32; ++i) {
        short2 kk = *(const short2*)(kexp + base + (size_t)i * NA);
        short2 vv = *(const short2*)(vbuf + base + (size_t)i * NA);
        float ke0 = bf2f(kk.x), ke1 = bf2f(kk.y);
        float a = ap[i];
        S0 = S0 * r + ke0 * bf2f(vv.x) * a;
        S1 = S1 * r + ke1 * bf2f(vv.y) * a;
        ks0 += ke0; ks1 += ke1;
    }
    *(float4*)&states[(size_t)seg * 4096 + col] = make_float4(S0, ks0, S1, ks1);
    __threadfence();                     // make aggregate device-visible
    __syncthreads();                     // all threads published
    if (tid == 0)
        __hip_atomic_store(&flags[bid], MAGIC, __ATOMIC_RELEASE,
                           __HIP_MEMORY_SCOPE_AGENT);

    // ---- phase 2: lookback combine (exclusive prefix) ----
    float rp = r;
    #pragma unroll
    for (int i = 0; i < 5; ++i) rp = rp * rp;   // r^32
    float P0 = 0.f, Pk0 = 0.f, P1 = 0.f, Pk1 = 0.f;
    for (int s = 0; s < seg; ++s) {
        if (tid == 0) {
            while (__hip_atomic_load(&flags[(s << 3) | g], __ATOMIC_ACQUIRE,
                                     __HIP_MEMORY_SCOPE_AGENT) != MAGIC) {}
        }
        __syncthreads();
        float4 st = *(const float4*)&states[(size_t)s * 4096 + col];
        P0 = P0 * rp + st.x;  Pk0 += st.y;
        P1 = P1 * rp + st.z;  Pk1 += st.w;
    }

    // ---- emit outputs with incoming prefix (slice is L1/L2-hot) ----
    S0 = P0; ks0 = Pk0; S1 = P1; ks1 = Pk1;
    const float* bp = beta + h * Tn + t0;
    #pragma unroll 4
    for (int i = 0; i < 32; ++i) {
        size_t idx = base + (size_t)i * NA;
        short2 kk = *(const short2*)(kexp + idx);
        short2 vv = *(const short2*)(vbuf + idx);
        short2 ss = *(const short2*)(sigr + idx);
        float a = ap[i], bt = bp[i];
        float ke0 = bf2f(kk.x), ke1 = bf2f(kk.y);
        S0 = S0 * r + ke0 * bf2f(vv.x) * a;
        S1 = S1 * r + ke1 * bf2f(vv.y) * a;
        ks0 += ke0; ks1 += ke1;
        short2 o;
        o.x = f2bf(bf2f(ss.x) * bt * S0 * __builtin_amdgcn_rcpf(ks0));
        o.y = f2bf(bf2f(ss.y) * bt * S1 * __builtin_amdgcn_rcpf(ks1));
        *(short2*)(out + idx) = o;
    }
}

// ---------------------------------------------------------------------------
extern "C" void kernel_launch(void* const* d_in, const int* in_sizes, int n_in,
                              void* d_out, int out_size, void* d_ws, size_t ws_size,
                              hipStream_t stream)
{
    const float* x      = (const float*)d_in[0];
    const float* time_w = (const float*)d_in[1];
    const float* alpha  = (const float*)d_in[2];
    const float* beta   = (const float*)d_in[3];
    const float* gamma  = (const float*)d_in[4];
    const float* Wk     = (const float*)d_in[5];
    const float* bk     = (const float*)d_in[6];
    const float* Wv     = (const float*)d_in[7];
    const float* bv     = (const float*)d_in[8];
    const float* Wr     = (const float*)d_in[9];
    const float* br     = (const float*)d_in[10];
    const float* Wo     = (const float*)d_in[11];
    const float* bo     = (const float*)d_in[12];
    float* out = (float*)d_out;

    char* ws = (char*)d_ws;

    // Workspace layout (<= 64 MB):
    short*    kbuf  = (short*)(ws);                 //  8 MB @ 0   exp(k) bf16
    short*    vbuf  = (short*)(ws + ( 8u << 20));   //  8 MB @ 8   v bf16
    short*    sbuf  = (short*)(ws + (16u << 20));   //  8 MB @ 16  sigmoid(r) bf16
    short*    xsbuf = (short*)(ws + (24u << 20));   //  8 MB @ 24  xs bf16 -> rwkv bf16
    short*    Wt    = (short*)(ws + (32u << 20));   //  8 MB @ 32  [Wk^T|Wv^T|Wr^T|Wo^T]
    float2*   states= (float2*)(ws + (40u << 20));  //  1 MB
    unsigned* flags = (unsigned*)(ws + (41u << 20));//  1 KB

    dim3 thr(256);

    prep<<<dim3(8192), thr, 0, stream>>>(x, Wk, Wv, Wr, Wo, xsbuf, Wt, flags);

    // fused K/V/R GEMM: N = 3072, 768 blocks = 3/CU (XCD-swizzled inside)
    gemm_db<0, 128><<<dim3(768), thr, 0, stream>>>(
        xsbuf, Wt, bk, bv, br, kbuf, vbuf, sbuf, nullptr, nullptr);

    // single-pass decoupled-lookback scan (replaces scanA + scanC)
    scan_fused<<<dim3(256), thr, 0, stream>>>(
        kbuf, vbuf, sbuf, time_w, alpha, beta, states, flags, xsbuf);

    // output GEMM: tile 128x64, 512 blocks
    gemm_db<1, 64><<<dim3(512), thr, 0, stream>>>(
        xsbuf, Wt + (size_t)3 * 1024 * 1024, bo, nullptr, nullptr,
        nullptr, nullptr, nullptr, out, gamma);
}

// Round 12
// 174.396 us; speedup vs baseline: 1.3488x; 1.3488x over previous
//
#include <hip/hip_runtime.h>
#include <hip/hip_bf16.h>
#include <cstddef>
#include <cstdint>

// Problem constants
#define Bn   4
#define Tn   1024
#define HID  1024
#define NH   64
#define HS   16
#define NA   1024

typedef short v8s __attribute__((ext_vector_type(8)));
typedef float v4f __attribute__((ext_vector_type(4)));

typedef __attribute__((address_space(1))) void* as1_void;
typedef __attribute__((address_space(3))) void* as3_void;

__device__ __forceinline__ void gload_lds16(const void* g, void* l) {
    __builtin_amdgcn_global_load_lds((as1_void)(void*)g, (as3_void)l, 16, 0, 0);
}

__device__ __forceinline__ short f2bf(float f) {
    __hip_bfloat16 h = __float2bfloat16(f);
    return *reinterpret_cast<short*>(&h);
}
__device__ __forceinline__ float bf2f(short s) {
    __hip_bfloat16 h = *reinterpret_cast<__hip_bfloat16*>(&s);
    return __bfloat162float(h);
}

// ---------------------------------------------------------------------------
// prep: fused build_xs (blocks 0..4095) + weight transpose/convert (4096..8191)
// ---------------------------------------------------------------------------
__global__ __launch_bounds__(256)
void prep(const float* __restrict__ x,
          const float* __restrict__ W0, const float* __restrict__ W1,
          const float* __restrict__ W2, const float* __restrict__ W3,
          short* __restrict__ xs, short* __restrict__ Wt)
{
    __shared__ float tile[32][33];
    const int bid = blockIdx.x;
    const int tid = threadIdx.x;
    if (bid < 4096) {
        int idx = bid * 256 + tid;
        int m  = idx >> 8;
        int c4 = (idx & 255) * 4;
        int t  = m & (Tn - 1);
        float4 v;
        if (c4 < HID / 2) {
            if (t == 0) v = make_float4(0.f, 0.f, 0.f, 0.f);
            else        v = *(const float4*)(x + (size_t)(m - 1) * HID + c4);
        } else {
            v = *(const float4*)(x + (size_t)m * HID + c4);
        }
        short4 o;
        o.x = f2bf(v.x); o.y = f2bf(v.y); o.z = f2bf(v.z); o.w = f2bf(v.w);
        *(short4*)(xs + (size_t)m * HID + c4) = o;
    } else {
        int b2 = bid - 4096;
        int z  = b2 >> 10;
        int rem = b2 & 1023;
        const float* W = (z == 0) ? W0 : (z == 1) ? W1 : (z == 2) ? W2 : W3;
        short* dst = Wt + (size_t)z * 1024 * 1024;
        int k0 = (rem & 31) * 32;
        int n0 = (rem >> 5) * 32;
        int tx = tid & 31;
        int ty = tid >> 5;
        #pragma unroll
        for (int j = 0; j < 4; ++j)
            tile[ty + 8 * j][tx] = W[(size_t)(k0 + ty + 8 * j) * NA + n0 + tx];
        __syncthreads();
        #pragma unroll
        for (int j = 0; j < 4; ++j)
            dst[(size_t)(n0 + ty + 8 * j) * HID + k0 + tx] = f2bf(tile[tx][ty + 8 * j]);
    }
}

// ---------------------------------------------------------------------------
// Round-7 measured-best MFMA GEMM: 2-stage double-buffer, tile 128 x TN,
// BK=32, 256 thr = 4 waves; vmcnt(N>0) prefetch + raw barriers.
// SWAPPED-OPERAND mfma(bfr, af, acc): acc[mt][nt][reg] =
//   C[m = wm+mt*16+(lane&15)][n = wn+nt*16+(lane>>4)*4+reg] -> packed stores.
// LDS rows 32 shorts, chunk swizzle slot=(q+(r>>1))&3, inverse in gather.
// EPI 0 (TN=128, KVR fused, type=bn>>10): via LDS transpose tile, int4 stores.
// EPI 1 (TN=64): fout = (acc + b0[n]) * gamma[m&1023], float4 stores.
// ---------------------------------------------------------------------------
template<int EPI, int TN>
__global__ __launch_bounds__(256)
void gemm_db(const short* __restrict__ A, const short* __restrict__ Bt,
             const float* __restrict__ b0, const float* __restrict__ b1,
             const float* __restrict__ b2,
             short* __restrict__ kout, short* __restrict__ vout,
             short* __restrict__ sout, float* __restrict__ fout,
             const float* __restrict__ gamma)
{
    constexpr int NT = TN / 32;          // n-tiles per wave
    constexpr int BI = TN / 64;          // B staging insts per wave
    constexpr int STAGE = 2 * 128 * 32 + 2 * TN * 32;
    constexpr int TILE  = (EPI == 0) ? 128 * 136 : 0;   // transpose tile
    constexpr int SMEM  = STAGE > TILE ? STAGE : TILE;
    __shared__ short smem[SMEM];
    short* As = smem;                    // [2][128*32]
    short* Bs = smem + 2 * 128 * 32;     // [2][TN*32]

    const int tid  = threadIdx.x;
    const int wave = tid >> 6;
    const int lane = tid & 63;

    // XCD-friendly block swizzle
    int id = blockIdx.x;
    int brow, bcol;
    if (TN == 128) { int grp = id / 192, l = id % 192; brow = grp * 8 + (l & 7); bcol = (l >> 3) % 24; }
    else           { int grp = id / 128, l = id % 128; brow = grp * 8 + (l & 7); bcol = l >> 3; }
    const int bm = brow * 128;
    const int bn = bcol * TN;

    const int wm = (wave & 1) * 64;
    const int wn = (wave >> 1) * (TN / 2);
    const int lm = lane & 15;
    const int lq = lane >> 4;
    const int lr = lane >> 2;            // 16 rows per staging inst
    const int l4 = lane & 3;             // chunk slot within row

    v4f acc[4][NT];
    #pragma unroll
    for (int i = 0; i < 4; ++i)
        #pragma unroll
        for (int j = 0; j < NT; ++j) acc[i][j] = (v4f){0.f, 0.f, 0.f, 0.f};

    // staging pointers with inverse swizzle q = (slot - (r>>1)) & 3
    const short* ag[2];
    int adst[2];
    #pragma unroll
    for (int i = 0; i < 2; ++i) {
        int r = wave * 32 + i * 16 + lr;
        int q = (l4 - (r >> 1)) & 3;
        ag[i]  = A + (size_t)(bm + r) * 1024 + q * 8;
        adst[i] = (wave * 32 + i * 16) * 32;        // wave-uniform base
    }
    const short* bg[BI];
    int bdst[BI];
    #pragma unroll
    for (int i = 0; i < BI; ++i) {
        int r = wave * (TN / 4) + i * 16 + lr;
        int q = (l4 - (r >> 1)) & 3;
        bg[i]  = Bt + (size_t)(bn + r) * 1024 + q * 8;
        bdst[i] = (wave * (TN / 4) + i * 16) * 32;
    }
    // fragment LDS offsets: chunk lq of row r at slot (lq + (r>>1)) & 3
    int afo[4], bfo[NT];
    #pragma unroll
    for (int t = 0; t < 4; ++t) {
        int r = wm + t * 16 + lm;
        afo[t] = r * 32 + ((lq + (r >> 1)) & 3) * 8;
    }
    #pragma unroll
    for (int nt = 0; nt < NT; ++nt) {
        int r = wn + nt * 16 + lm;
        bfo[nt] = r * 32 + ((lq + (r >> 1)) & 3) * 8;
    }

    // prologue: stage k=0 into buffer 0
    #pragma unroll
    for (int i = 0; i < 2; ++i)  gload_lds16(ag[i],  &As[adst[i]]);
    #pragma unroll
    for (int i = 0; i < BI; ++i) gload_lds16(bg[i],  &Bs[bdst[i]]);

    #pragma unroll 2
    for (int it = 0; it < 32; ++it) {
        const int cur = it & 1;
        if (it < 31) {
            int k1 = (it + 1) * 32;
            int nxt = cur ^ 1;
            #pragma unroll
            for (int i = 0; i < 2; ++i)
                gload_lds16(ag[i] + k1, &As[nxt * 4096 + adst[i]]);
            #pragma unroll
            for (int i = 0; i < BI; ++i)
                gload_lds16(bg[i] + k1, &Bs[nxt * TN * 32 + bdst[i]]);
            asm volatile("s_waitcnt vmcnt(%0)" :: "i"(2 + BI) : "memory");
        } else {
            asm volatile("s_waitcnt vmcnt(0)" ::: "memory");
        }
        asm volatile("s_barrier" ::: "memory");

        v8s af[4], bfr[NT];
        #pragma unroll
        for (int t = 0; t < 4; ++t)
            af[t] = *(const v8s*)&As[cur * 4096 + afo[t]];
        #pragma unroll
        for (int nt = 0; nt < NT; ++nt)
            bfr[nt] = *(const v8s*)&Bs[cur * TN * 32 + bfo[nt]];
        #pragma unroll
        for (int mt = 0; mt < 4; ++mt)
            #pragma unroll
            for (int nt = 0; nt < NT; ++nt)
                acc[mt][nt] = __builtin_amdgcn_mfma_f32_16x16x32_bf16(
                    bfr[nt], af[mt], acc[mt][nt], 0, 0, 0);

        asm volatile("s_barrier" ::: "memory");   // protect cur before restage
    }

    if (EPI == 0) {
        __syncthreads();                 // staging LDS now dead; reuse as tile
        short* tile = smem;              // 128 rows x stride 136 shorts
        const int type = bn >> 10;
        const int cb = bn & 1023;
        const float* bias = (type == 0) ? b0 : (type == 1) ? b1 : b2;
        #pragma unroll
        for (int mt = 0; mt < 4; ++mt) {
            int ml = wm + mt * 16 + lm;
            #pragma unroll
            for (int nt = 0; nt < NT; ++nt) {
                int nl = wn + nt * 16 + lq * 4;
                float4 bv4 = *(const float4*)&bias[cb + nl];
                short4 o;
                #pragma unroll
                for (int r = 0; r < 4; ++r) {
                    float v = acc[mt][nt][r] + ((const float*)&bv4)[r];
                    if (type == 0) {
                        v = fminf(fmaxf(v, -60.f), 30.f);
                        v = __expf(v);
                    } else if (type == 2) {
                        v = __builtin_amdgcn_rcpf(1.f + __expf(-v));
                    }
                    ((short*)&o)[r] = f2bf(v);
                }
                *(short4*)&tile[ml * 136 + nl] = o;
            }
        }
        __syncthreads();
        short* outp = (type == 0) ? kout : (type == 1) ? vout : sout;
        const int rml = tid >> 4;
        const int rnl = (tid & 15) * 8;
        #pragma unroll
        for (int p = 0; p < 8; ++p) {
            int ml = p * 16 + rml;
            int4 d = *(const int4*)&tile[ml * 136 + rnl];
            *(int4*)&outp[(size_t)(bm + ml) * 1024 + cb + rnl] = d;
        }
    } else {
        #pragma unroll
        for (int mt = 0; mt < 4; ++mt) {
            int m = bm + wm + mt * 16 + lm;
            float g = gamma[m & (Tn - 1)];
            #pragma unroll
            for (int nt = 0; nt < NT; ++nt) {
                int n0 = bn + wn + nt * 16 + lq * 4;
                float4 bv4 = *(const float4*)&b0[n0];
                float4 o;
                o.x = (acc[mt][nt][0] + bv4.x) * g;
                o.y = (acc[mt][nt][1] + bv4.y) * g;
                o.z = (acc[mt][nt][2] + bv4.z) * g;
                o.w = (acc[mt][nt][3] + bv4.w) * g;
                *(float4*)&fout[(size_t)m * 1024 + n0] = o;
            }
        }
    }
}

// ---------------------------------------------------------------------------
// Round-8 two-pass linear-recurrence scan (geometric time_w):
// w[t,u] = r_h^(t-u), r_h = time_w[h,1022].
//   S[t] = r*S[t-1] + alpha[t]*kexp[t]*v[t];  ks[t] = ks[t-1] + kexp[t]
// 32 segments x 32 t; each thread 2 channels; 256 blocks/pass = 1/CU.
// passC folds the cross-segment exclusive combine inline.
// ---------------------------------------------------------------------------
#define SEG 32
#define SEGL 32

__global__ __launch_bounds__(256)
void scan_passA(const short* __restrict__ kexp, const short* __restrict__ vbuf,
                const float* __restrict__ time_w, const float* __restrict__ alpha,
                float2* __restrict__ states)
{
    int gid = blockIdx.x * 256 + threadIdx.x;      // 0..65535
    int c2  = (gid & 511) * 2;
    int b   = (gid >> 9) & 3;
    int seg = gid >> 11;                           // 0..31
    int h   = c2 >> 4;
    float r = time_w[h * Tn + (Tn - 2)];
    int t0 = seg * SEGL;
    size_t base = ((size_t)(b * Tn + t0)) * NA + c2;
    const float* ap = alpha + h * Tn + t0;
    float S0 = 0.f, S1 = 0.f, ks0 = 0.f, ks1 = 0.f;
    #pragma unroll 4
    for (int i = 0; i < SEGL; ++i) {
        short2 kk = *(const short2*)(kexp + base + (size_t)i * NA);
        short2 vv = *(const short2*)(vbuf + base + (size_t)i * NA);
        float ke0 = bf2f(kk.x), ke1 = bf2f(kk.y);
        float a = ap[i];
        S0 = S0 * r + ke0 * bf2f(vv.x) * a;
        S1 = S1 * r + ke1 * bf2f(vv.y) * a;
        ks0 += ke0; ks1 += ke1;
    }
    int sidx = seg * 4096 + b * 1024 + c2;
    *(float4*)&states[sidx] = make_float4(S0, ks0, S1, ks1);
}

__global__ __launch_bounds__(256)
void scan_passC(const short* __restrict__ kexp, const short* __restrict__ vbuf,
                const short* __restrict__ sigr,
                const float* __restrict__ time_w, const float* __restrict__ alpha,
                const float* __restrict__ beta,
                const float2* __restrict__ states, short* __restrict__ out)
{
    int gid = blockIdx.x * 256 + threadIdx.x;
    int c2  = (gid & 511) * 2;
    int b   = (gid >> 9) & 3;
    int seg = gid >> 11;
    int h   = c2 >> 4;
    float r = time_w[h * Tn + (Tn - 2)];
    float rp = r;
    #pragma unroll
    for (int i = 0; i < 5; ++i) rp = rp * rp;      // r^32
    // inline exclusive combine over earlier segments
    float S0 = 0.f, ks0 = 0.f, S1 = 0.f, ks1 = 0.f;
    for (int s = 0; s < seg; ++s) {
        float4 st = *(const float4*)&states[s * 4096 + b * 1024 + c2];
        S0 = S0 * rp + st.x;  ks0 += st.y;
        S1 = S1 * rp + st.z;  ks1 += st.w;
    }
    int t0 = seg * SEGL;
    size_t base = ((size_t)(b * Tn + t0)) * NA + c2;
    const float* ap = alpha + h * Tn + t0;
    const float* bp = beta  + h * Tn + t0;
    #pragma unroll 4
    for (int i = 0; i < SEGL; ++i) {
        size_t idx = base + (size_t)i * NA;
        short2 kk = *(const short2*)(kexp + idx);
        short2 vv = *(const short2*)(vbuf + idx);
        short2 ss = *(const short2*)(sigr + idx);
        float a = ap[i], bt = bp[i];
        float ke0 = bf2f(kk.x), ke1 = bf2f(kk.y);
        S0 = S0 * r + ke0 * bf2f(vv.x) * a;
        S1 = S1 * r + ke1 * bf2f(vv.y) * a;
        ks0 += ke0; ks1 += ke1;
        short2 o;
        o.x = f2bf(bf2f(ss.x) * bt * S0 * __builtin_amdgcn_rcpf(ks0));
        o.y = f2bf(bf2f(ss.y) * bt * S1 * __builtin_amdgcn_rcpf(ks1));
        *(short2*)(out + idx) = o;
    }
}

// ---------------------------------------------------------------------------
extern "C" void kernel_launch(void* const* d_in, const int* in_sizes, int n_in,
                              void* d_out, int out_size, void* d_ws, size_t ws_size,
                              hipStream_t stream)
{
    const float* x      = (const float*)d_in[0];
    const float* time_w = (const float*)d_in[1];
    const float* alpha  = (const float*)d_in[2];
    const float* beta   = (const float*)d_in[3];
    const float* gamma  = (const float*)d_in[4];
    const float* Wk     = (const float*)d_in[5];
    const float* bk     = (const float*)d_in[6];
    const float* Wv     = (const float*)d_in[7];
    const float* bv     = (const float*)d_in[8];
    const float* Wr     = (const float*)d_in[9];
    const float* br     = (const float*)d_in[10];
    const float* Wo     = (const float*)d_in[11];
    const float* bo     = (const float*)d_in[12];
    float* out = (float*)d_out;

    char* ws = (char*)d_ws;

    // Workspace layout (<= 64 MB):
    short*  kbuf  = (short*)(ws);                 //  8 MB @ 0   exp(k) bf16
    short*  vbuf  = (short*)(ws + ( 8u << 20));   //  8 MB @ 8   v bf16
    short*  sbuf  = (short*)(ws + (16u << 20));   //  8 MB @ 16  sigmoid(r) bf16
    short*  xsbuf = (short*)(ws + (24u << 20));   //  8 MB @ 24  xs bf16 -> rwkv bf16
    short*  Wt    = (short*)(ws + (32u << 20));   //  8 MB @ 32  [Wk^T|Wv^T|Wr^T|Wo^T]
    float2* states= (float2*)(ws + (40u << 20));  //  1 MB

    dim3 thr(256);

    prep<<<dim3(8192), thr, 0, stream>>>(x, Wk, Wv, Wr, Wo, xsbuf, Wt);

    // fused K/V/R GEMM: N = 3072, 768 blocks = 3/CU (XCD-swizzled inside)
    gemm_db<0, 128><<<dim3(768), thr, 0, stream>>>(
        xsbuf, Wt, bk, bv, br, kbuf, vbuf, sbuf, nullptr, nullptr);

    scan_passA<<<dim3(256), thr, 0, stream>>>(kbuf, vbuf, time_w, alpha, states);
    scan_passC<<<dim3(256), thr, 0, stream>>>(kbuf, vbuf, sbuf,
                                              time_w, alpha, beta, states, xsbuf);

    // output GEMM: tile 128x64, 512 blocks
    gemm_db<1, 64><<<dim3(512), thr, 0, stream>>>(
        xsbuf, Wt + (size_t)3 * 1024 * 1024, bo, nullptr, nullptr,
        nullptr, nullptr, nullptr, out, gamma);
}